// Round 13
// baseline (382.880 us; speedup 1.0000x reference)
//
#include <hip/hip_runtime.h>

// FrequencyAwareSpatialAttention via MFMA.
// R13: max-occupancy register-staged structure (R7 lineage).
//   - frq UNPADDED: 289 pixel rows + shared zero-row 289 => 37.1 KB LDS
//     => 4 blocks/CU; __launch_bounds__(512,8) caps VGPR at 64 (compiler
//     sits at ~52 anyway) => 32 waves/CU = 100% occupancy. R12 proved
//     1 block/CU (big-LDS DMA) exposes all latency; R8-R10 proved per-wave
//     load depth is compiler-pinned ~4 => scale WAVES, not depth.
//   - sobel structure fast-path (runtime-verified, general fallback):
//     middle col 0, col0 = -col2  =>  s = sw2*top+sw5*mid+sw8*bot,
//     o = shl1(s) - shr1(s). ~45% staging-VALU cut.
//   - DPP wave shifts, v_cvt_pk_bf16_f32, uniform sobel weights,
//     XCD-chunked swizzle: all carried over (validated).
// conv 64->16 3x3 (pad 1): 9 offsets x 2 mfma_f32_16x16x32_bf16 (K=64),
// zero-row for out-of-window taps; +b1, relu, 1x1 conv +b2, sigmoid, clip.

#define WSZ 17
#define NT  512           // 8 waves
#define CH  (510 * 510)   // floats per channel plane

typedef __attribute__((ext_vector_type(8))) short bf16x8;
typedef __attribute__((ext_vector_type(4))) float f32x4;
typedef __attribute__((ext_vector_type(2))) float f32x2;

// XOR swizzle: involution within each 128B frq row (row = pixel index).
__device__ __forceinline__ int swz(int off) {
    return off ^ (((off >> 7) & 7) << 4);
}

__device__ __forceinline__ unsigned short f2bf(float f) {
    union { float f; unsigned u; } v; v.f = f;
    unsigned u = v.u;
    unsigned r = u + 0x7fffu + ((u >> 16) & 1u);   // RNE
    return (unsigned short)(r >> 16);
}

// lane i <- lane i-1 (wave_shr:1), lane 0 <- 0
__device__ __forceinline__ float dpp_shr1(float v) {
    return __int_as_float(
        __builtin_amdgcn_update_dpp(0, __float_as_int(v), 0x138, 0xf, 0xf, true));
}
// lane i <- lane i+1 (wave_shl:1), lane 63 <- 0
__device__ __forceinline__ float dpp_shl1(float v) {
    return __int_as_float(
        __builtin_amdgcn_update_dpp(0, __float_as_int(v), 0x130, 0xf, 0xf, true));
}

// Pre-kernel: transpose+convert w1 [16][64][3][3] fp32 into A-fragment order.
// Fragment (dij, ks): lane l holds A[m = l&15][k = ks*32 + 8*(l>>4) + j], j=0..7.
__global__ void prep_w1(const float* __restrict__ w1, unsigned short* __restrict__ wt) {
    const int dij = blockIdx.x >> 1;
    const int ks  = blockIdx.x & 1;
    const int l   = threadIdx.x;           // 0..63
    const int m   = l & 15;
    const int kb  = ks * 32 + 8 * (l >> 4);
    bf16x8 v;
#pragma unroll
    for (int jj = 0; jj < 8; ++jj)
        v[jj] = (short)f2bf(w1[m * 576 + (kb + jj) * 9 + dij]);
    ((bf16x8*)wt)[blockIdx.x * 64 + l] = v;
}

__global__ __launch_bounds__(NT, 8)
void fasa_mfma(const float* __restrict__ x,
               const float* __restrict__ sobel_w,
               const unsigned short* __restrict__ wt,
               const float* __restrict__ b1,
               const float* __restrict__ w2,
               const float* __restrict__ b2,
               float* __restrict__ out)
{
    // frq: rows 0..288 = pixels (i*17+j), row 289 = shared zero row
    __shared__ __align__(16) char frq[290 * 128];      // 37120 B => 4 blocks/CU

    const int t    = threadIdx.x;
    const int lane = t & 63;
    const int wave = __builtin_amdgcn_readfirstlane(t >> 6);

    // XCD-chunked swizzle (bijective, 3600 = 8*450)
    const int bid = blockIdx.x;
    const int win = (bid & 7) * 450 + (bid >> 3);   // b*900 + wh*30 + ww
    const int b   = win / 900;
    const int rem = win % 900;
    const int h0  = (rem / 30) * WSZ;
    const int w0  = (rem % 30) * WSZ;

    // zero row 289 of frq (ordered by the pre-MFMA barrier)
    if (t < 8) *(f32x4*)(frq + 289 * 128 + t * 16) = (f32x4){0.f, 0.f, 0.f, 0.f};

    // sobel weights: all channels share one 3x3 (tiled in setup) -> scalar
    const float sw0 = sobel_w[0], sw1 = sobel_w[1], sw2 = sobel_w[2];
    const float sw3 = sobel_w[3], sw4 = sobel_w[4], sw5 = sobel_w[5];
    const float sw6 = sobel_w[6], sw7 = sobel_w[7], sw8 = sobel_w[8];
    // structure check (wave-uniform scalar branch): mid col zero, col0=-col2
    const bool fast = (sw1 == 0.f) && (sw4 == 0.f) && (sw7 == 0.f) &&
                      (sw0 == -sw2) && (sw3 == -sw5) && (sw6 == -sw8);

    const int j   = lane & 31;       // column, active when j < 17
    const int grp = lane >> 5;       // which pair of this wave's two
    const bool jac = (j < 17);

    // wave-uniform base (channel 4*wave); per-lane 32-bit byte offsets
    const float* xbase = x + ((size_t)(b * 64 + 4 * wave)) * CH
                           + (size_t)h0 * 510 + w0;
    const unsigned voffx = (unsigned)((grp * 2 * CH + j) * 4);
    const unsigned voffy = voffx + (unsigned)(CH * 4);

    auto LOADCOL = [&](f32x2* xr, int q) {
        const char* bp = (const char*)(xbase + (size_t)q * 32 * CH);
#pragma unroll
        for (int i = 0; i < 17; ++i) xr[i] = (f32x2){0.f, 0.f};
        if (jac) {
#pragma unroll
            for (int i = 0; i < 17; ++i) {
                xr[i].x = *(const float*)(bp + (voffx + (unsigned)i * 2040u));
                xr[i].y = *(const float*)(bp + (voffy + (unsigned)i * 2040u));
            }
        }
    };

    // general sobel: o = shr1(p0) + p1 + shl1(p2)
    auto SOBG = [&](const f32x2* xr, int q) {
        const int pr = 2 * wave + grp + 16 * q;       // pair index 0..31
#pragma unroll
        for (int i = 0; i < 17; ++i) {
            f32x2 top = (i > 0)  ? xr[i - 1] : (f32x2){0.f, 0.f};
            f32x2 mid = xr[i];
            f32x2 bot = (i < 16) ? xr[i + 1] : (f32x2){0.f, 0.f};
            f32x2 p0 = sw0 * top + sw3 * mid + sw6 * bot;
            f32x2 p1 = sw1 * top + sw4 * mid + sw7 * bot;
            f32x2 p2 = sw2 * top + sw5 * mid + sw8 * bot;
            f32x2 o;
            o.x = p1.x + dpp_shr1(p0.x) + dpp_shl1(p2.x);
            o.y = p1.y + dpp_shr1(p0.y) + dpp_shl1(p2.y);
            unsigned pkv;
            asm("v_cvt_pk_bf16_f32 %0, %1, %2" : "=v"(pkv) : "v"(o.x), "v"(o.y));
            if (jac)
                *(unsigned*)(frq + swz((i * 17 + j) * 128 + pr * 4)) = pkv;
        }
    };

    // fast sobel (mid col 0, col0 = -col2): s = sw2*top+sw5*mid+sw8*bot,
    // o = shl1(s) - shr1(s). Zero cols at j>=17 supply window pads via DPP.
    auto SOBF = [&](const f32x2* xr, int q) {
        const int pr = 2 * wave + grp + 16 * q;
#pragma unroll
        for (int i = 0; i < 17; ++i) {
            f32x2 top = (i > 0)  ? xr[i - 1] : (f32x2){0.f, 0.f};
            f32x2 mid = xr[i];
            f32x2 bot = (i < 16) ? xr[i + 1] : (f32x2){0.f, 0.f};
            f32x2 s = sw2 * top + sw5 * mid + sw8 * bot;
            f32x2 o;
            o.x = dpp_shl1(s.x) - dpp_shr1(s.x);
            o.y = dpp_shl1(s.y) - dpp_shr1(s.y);
            unsigned pkv;
            asm("v_cvt_pk_bf16_f32 %0, %1, %2" : "=v"(pkv) : "v"(o.x), "v"(o.y));
            if (jac)
                *(unsigned*)(frq + swz((i * 17 + j) * 128 + pr * 4)) = pkv;
        }
    };

    // A/B staging (compiler schedules depth as it will; waves supply MLP)
    f32x2 A[17], B[17];
    LOADCOL(A, 0);
    LOADCOL(B, 1);
    if (fast) { SOBF(A, 0); SOBF(B, 1); }
    else      { SOBG(A, 0); SOBG(B, 1); }

    // ---- W fragments + epilogue constants ----
    bf16x8 wf[18];
#pragma unroll
    for (int i = 0; i < 18; ++i)
        wf[i] = ((const bf16x8*)wt)[i * 64 + lane];

    float b1v[4], w2v[4];
#pragma unroll
    for (int r = 0; r < 4; ++r) {
        int m = 4 * (lane >> 4) + r;
        b1v[r] = b1[m];
        w2v[r] = w2[m];
    }
    const float b2v = b2[0];

    __syncthreads();   // single barrier: frq complete across waves

    // ---- conv1 via MFMA: wave w handles pixel tiles {w, w+8, w+16} ----
    const int n   = lane & 15;          // pixel within tile (MFMA N)
    const int g16 = (lane >> 4) * 16;   // 8-channel chunk byte offset

#pragma unroll 1
    for (int nt = wave; nt < 19; nt += 8) {
        int p  = nt * 16 + n;
        int pv = p > 288 ? 288 : p;     // clamp dead lanes of last tile
        int pi = pv / 17, pj = pv - pi * 17;

        f32x4 acc = {0.f, 0.f, 0.f, 0.f};
#pragma unroll
        for (int d = 0; d < 9; ++d) {
            const int di = d / 3 - 1, dj = d % 3 - 1;      // compile-time
            bool ok = ((unsigned)(pi + di) < 17u) & ((unsigned)(pj + dj) < 17u);
            int row = ok ? (pv + di * 17 + dj) : 289;      // 289 = zero row
            int off = row * 128 + g16;
            bf16x8 bfA = *(const bf16x8*)(frq + swz(off));
            bf16x8 bfB = *(const bf16x8*)(frq + swz(off + 64));
            acc = __builtin_amdgcn_mfma_f32_16x16x32_bf16(wf[2 * d],     bfA, acc, 0, 0, 0);
            acc = __builtin_amdgcn_mfma_f32_16x16x32_bf16(wf[2 * d + 1], bfB, acc, 0, 0, 0);
        }

        float part = 0.f;
#pragma unroll
        for (int r = 0; r < 4; ++r)
            part = fmaf(w2v[r], fmaxf(acc[r] + b1v[r], 0.f), part);
        part += __shfl_xor(part, 16);
        part += __shfl_xor(part, 32);

        if (lane < 16 && p < 289) {
            float pre = part + b2v;
            float s = 1.f / (1.f + expf(-pre));
            s = fminf(fmaxf(s, 0.05f), 0.95f);
            out[((size_t)(b * 510 + h0 + pi)) * 510 + (w0 + pj)] = s;
        }
    }
}

extern "C" void kernel_launch(void* const* d_in, const int* in_sizes, int n_in,
                              void* d_out, int out_size, void* d_ws, size_t ws_size,
                              hipStream_t stream) {
    const float* x       = (const float*)d_in[0];
    const float* sobel_w = (const float*)d_in[1];
    const float* w1      = (const float*)d_in[2];
    const float* b1      = (const float*)d_in[3];
    const float* w2      = (const float*)d_in[4];
    const float* b2      = (const float*)d_in[5];
    float* out = (float*)d_out;
    unsigned short* wtab = (unsigned short*)d_ws;   // 18*64*16 = 18432 B

    prep_w1<<<dim3(18), dim3(64), 0, stream>>>(w1, wtab);
    fasa_mfma<<<dim3(3600), dim3(NT), 0, stream>>>(x, sobel_w, wtab, b1, w2, b2, out);
}

// Round 14
// 97.439 us; speedup vs baseline: 3.9294x; 3.9294x over previous
//
#include <hip/hip_runtime.h>

// FrequencyAwareSpatialAttention via MFMA.
// R14: ROWS-IN-LANES staging — the first structure where staging loads
// vectorize. Lane (grp, i) holds window row i of a channel pair; rows are
// contiguous => 5 float4 loads per channel (4x bytes/instr at the same
// compiler-pinned load depth that R8-R12 proved immovable).
// Sobel axes swapped: (1,2,1) smoothing VERTICAL via DPP wave_shr/shl
// (lane i+-1 = row i+-1; lanes 17..31 hold zero rows = pads), (-1,0,1)
// difference HORIZONTAL in-register, rolling window: out_j = s_{j+1}-s_{j-1}.
// General-weights fallback kept (runtime wave-uniform check).
// frq unpadded 289 rows + zero-row 289 (37.1 KB, validated R11-R13).
// conv 64->16 3x3 (pad 1): 9 offsets x 2 mfma_f32_16x16x32_bf16 (K=64);
// +b1, relu, 1x1 conv +b2, sigmoid, clip, scatter. XCD-chunked swizzle.

#define NT  512           // 8 waves
#define CH  (510 * 510)   // floats per channel plane

typedef __attribute__((ext_vector_type(8))) short bf16x8;
typedef __attribute__((ext_vector_type(4))) float f32x4;

// XOR swizzle: involution within each 128B frq row (row = pixel index).
__device__ __forceinline__ int swz(int off) {
    return off ^ (((off >> 7) & 7) << 4);
}

__device__ __forceinline__ unsigned short f2bf(float f) {
    union { float f; unsigned u; } v; v.f = f;
    unsigned u = v.u;
    unsigned r = u + 0x7fffu + ((u >> 16) & 1u);   // RNE
    return (unsigned short)(r >> 16);
}

// lane i <- lane i-1 (wave_shr:1), lane 0 <- 0
__device__ __forceinline__ float dpp_shr1(float v) {
    return __int_as_float(
        __builtin_amdgcn_update_dpp(0, __float_as_int(v), 0x138, 0xf, 0xf, true));
}
// lane i <- lane i+1 (wave_shl:1), lane 63 <- 0
__device__ __forceinline__ float dpp_shl1(float v) {
    return __int_as_float(
        __builtin_amdgcn_update_dpp(0, __float_as_int(v), 0x130, 0xf, 0xf, true));
}

// Pre-kernel: transpose+convert w1 [16][64][3][3] fp32 into A-fragment order.
// Fragment (dij, ks): lane l holds A[m = l&15][k = ks*32 + 8*(l>>4) + j], j=0..7.
__global__ void prep_w1(const float* __restrict__ w1, unsigned short* __restrict__ wt) {
    const int dij = blockIdx.x >> 1;
    const int ks  = blockIdx.x & 1;
    const int l   = threadIdx.x;           // 0..63
    const int m   = l & 15;
    const int kb  = ks * 32 + 8 * (l >> 4);
    bf16x8 v;
#pragma unroll
    for (int jj = 0; jj < 8; ++jj)
        v[jj] = (short)f2bf(w1[m * 576 + (kb + jj) * 9 + dij]);
    ((bf16x8*)wt)[blockIdx.x * 64 + l] = v;
}

__global__ __launch_bounds__(NT, 4)
void fasa_mfma(const float* __restrict__ x,
               const float* __restrict__ sobel_w,
               const unsigned short* __restrict__ wt,
               const float* __restrict__ b1,
               const float* __restrict__ w2,
               const float* __restrict__ b2,
               float* __restrict__ out)
{
    // frq: rows 0..288 = pixels (i*17+j), row 289 = shared zero row
    __shared__ __align__(16) char frq[290 * 128];      // 37120 B

    const int t    = threadIdx.x;
    const int lane = t & 63;
    const int wave = __builtin_amdgcn_readfirstlane(t >> 6);

    // XCD-chunked swizzle (bijective, 3600 = 8*450)
    const int bid = blockIdx.x;
    const int win = (bid & 7) * 450 + (bid >> 3);   // b*900 + wh*30 + ww
    const int b   = win / 900;
    const int rem = win % 900;
    const int h0  = (rem / 30) * 17;
    const int w0  = (rem % 30) * 17;

    // zero row 289 of frq (ordered by the pre-MFMA barrier)
    if (t < 8) *(f32x4*)(frq + 289 * 128 + t * 16) = (f32x4){0.f, 0.f, 0.f, 0.f};

    // sobel weights: all channels share one 3x3 (tiled in setup) -> scalar
    const float sw0 = sobel_w[0], sw1 = sobel_w[1], sw2 = sobel_w[2];
    const float sw3 = sobel_w[3], sw4 = sobel_w[4], sw5 = sobel_w[5];
    const float sw6 = sobel_w[6], sw7 = sobel_w[7], sw8 = sobel_w[8];
    // fast path: middle column zero, col0 = -col2 (true for Sobel)
    const bool fast = (sw1 == 0.f) && (sw4 == 0.f) && (sw7 == 0.f) &&
                      (sw0 == -sw2) && (sw3 == -sw5) && (sw6 == -sw8);

    const int i   = lane & 31;       // window ROW, active when i < 17
    const int grp = lane >> 5;       // which channel pair of this wave's two
    const bool iac = (i < 17);

    // row base (per-lane); harmless for inactive lanes (loads predicated)
    const float* xb = x + (size_t)b * 64 * CH + (size_t)(h0 + i) * 510 + w0;

    auto PROC = [&](int q) {
        const int pr = 2 * wave + grp + 16 * q;   // pair index 0..31
        const int cA = 2 * pr;                    // channels cA, cA+1
        f32x4 vA[5], vB[5];
#pragma unroll
        for (int k = 0; k < 5; ++k) {
            vA[k] = (f32x4){0.f, 0.f, 0.f, 0.f};
            vB[k] = (f32x4){0.f, 0.f, 0.f, 0.f};
        }
        if (iac) {
            const float* pA = xb + (size_t)cA * CH;
            const float* pB = pA + (size_t)CH;
#pragma unroll
            for (int k = 0; k < 4; ++k) {
                __builtin_memcpy(&vA[k], pA + 4 * k, 16);
                __builtin_memcpy(&vB[k], pB + 4 * k, 16);
            }
            // col 16 via overlapping load at col 13 (never out of bounds)
            __builtin_memcpy(&vA[4], pA + 13, 16);
            __builtin_memcpy(&vB[4], pB + 13, 16);
        }
        // r_c: col c -> vA[c>>2][c&3] (c<16), col 16 -> vA[4][3]; all const idx

        if (fast) {
            // s_j = sw2*row(i-1,j) + sw5*row(i,j) + sw8*row(i+1,j)  [DPP vertical]
            // out_j = s_{j+1} - s_{j-1}                             [in-lane]
            float sAp = 0.f, sBp = 0.f;      // s_{j-1}
            float sAc, sBc;                  // s_j (chain)
            {
                float rA = vA[0][0], rB = vB[0][0];
                sAc = fmaf(sw2, dpp_shr1(rA), fmaf(sw5, rA, sw8 * dpp_shl1(rA)));
                sBc = fmaf(sw2, dpp_shr1(rB), fmaf(sw5, rB, sw8 * dpp_shl1(rB)));
            }
#pragma unroll
            for (int j = 0; j < 17; ++j) {
                float sAn = 0.f, sBn = 0.f;  // s_{j+1}; col 17 pad -> 0
                if (j < 16) {
                    float rA = (j + 1 < 16) ? vA[(j + 1) >> 2][(j + 1) & 3] : vA[4][3];
                    float rB = (j + 1 < 16) ? vB[(j + 1) >> 2][(j + 1) & 3] : vB[4][3];
                    sAn = fmaf(sw2, dpp_shr1(rA), fmaf(sw5, rA, sw8 * dpp_shl1(rA)));
                    sBn = fmaf(sw2, dpp_shr1(rB), fmaf(sw5, rB, sw8 * dpp_shl1(rB)));
                }
                float oA = sAn - sAp;
                float oB = sBn - sBp;
                unsigned pkv;
                asm("v_cvt_pk_bf16_f32 %0, %1, %2" : "=v"(pkv) : "v"(oA), "v"(oB));
                if (iac)
                    *(unsigned*)(frq + swz((i * 17 + j) * 128 + pr * 4)) = pkv;
                sAp = sAc; sAc = sAn;
                sBp = sBc; sBc = sBn;
            }
        } else {
            // general: h^d_j = horizontal 3-tap with sobel row d on own row;
            // out_j = shr1(h0_j) + h1_j + shl1(h2_j)
            float rAm = 0.f, rBm = 0.f;
            float rAc = vA[0][0], rBc = vB[0][0];
#pragma unroll
            for (int j = 0; j < 17; ++j) {
                float rAn = 0.f, rBn = 0.f;
                if (j < 16) {
                    rAn = (j + 1 < 16) ? vA[(j + 1) >> 2][(j + 1) & 3] : vA[4][3];
                    rBn = (j + 1 < 16) ? vB[(j + 1) >> 2][(j + 1) & 3] : vB[4][3];
                }
                float hA0 = fmaf(sw0, rAm, fmaf(sw1, rAc, sw2 * rAn));
                float hA1 = fmaf(sw3, rAm, fmaf(sw4, rAc, sw5 * rAn));
                float hA2 = fmaf(sw6, rAm, fmaf(sw7, rAc, sw8 * rAn));
                float hB0 = fmaf(sw0, rBm, fmaf(sw1, rBc, sw2 * rBn));
                float hB1 = fmaf(sw3, rBm, fmaf(sw4, rBc, sw5 * rBn));
                float hB2 = fmaf(sw6, rBm, fmaf(sw7, rBc, sw8 * rBn));
                float oA = dpp_shr1(hA0) + hA1 + dpp_shl1(hA2);
                float oB = dpp_shr1(hB0) + hB1 + dpp_shl1(hB2);
                unsigned pkv;
                asm("v_cvt_pk_bf16_f32 %0, %1, %2" : "=v"(pkv) : "v"(oA), "v"(oB));
                if (iac)
                    *(unsigned*)(frq + swz((i * 17 + j) * 128 + pr * 4)) = pkv;
                rAm = rAc; rAc = rAn;
                rBm = rBc; rBc = rBn;
            }
        }
    };

    PROC(0);
    PROC(1);

    // ---- W fragments + epilogue constants ----
    bf16x8 wf[18];
#pragma unroll
    for (int k = 0; k < 18; ++k)
        wf[k] = ((const bf16x8*)wt)[k * 64 + lane];

    float b1v[4], w2v[4];
#pragma unroll
    for (int r = 0; r < 4; ++r) {
        int m = 4 * (lane >> 4) + r;
        b1v[r] = b1[m];
        w2v[r] = w2[m];
    }
    const float b2v = b2[0];

    __syncthreads();   // single barrier: frq complete across waves

    // ---- conv1 via MFMA: wave w handles pixel tiles {w, w+8, w+16} ----
    const int n   = lane & 15;          // pixel within tile (MFMA N)
    const int g16 = (lane >> 4) * 16;   // 8-channel chunk byte offset

#pragma unroll 1
    for (int nt = wave; nt < 19; nt += 8) {
        int p  = nt * 16 + n;
        int pv = p > 288 ? 288 : p;     // clamp dead lanes of last tile
        int pi = pv / 17, pj = pv - pi * 17;

        f32x4 acc = {0.f, 0.f, 0.f, 0.f};
#pragma unroll
        for (int d = 0; d < 9; ++d) {
            const int di = d / 3 - 1, dj = d % 3 - 1;      // compile-time
            bool ok = ((unsigned)(pi + di) < 17u) & ((unsigned)(pj + dj) < 17u);
            int row = ok ? (pv + di * 17 + dj) : 289;      // 289 = zero row
            int off = row * 128 + g16;
            bf16x8 bfA = *(const bf16x8*)(frq + swz(off));
            bf16x8 bfB = *(const bf16x8*)(frq + swz(off + 64));
            acc = __builtin_amdgcn_mfma_f32_16x16x32_bf16(wf[2 * d],     bfA, acc, 0, 0, 0);
            acc = __builtin_amdgcn_mfma_f32_16x16x32_bf16(wf[2 * d + 1], bfB, acc, 0, 0, 0);
        }

        float part = 0.f;
#pragma unroll
        for (int r = 0; r < 4; ++r)
            part = fmaf(w2v[r], fmaxf(acc[r] + b1v[r], 0.f), part);
        part += __shfl_xor(part, 16);
        part += __shfl_xor(part, 32);

        if (lane < 16 && p < 289) {
            float pre = part + b2v;
            float s = 1.f / (1.f + expf(-pre));
            s = fminf(fmaxf(s, 0.05f), 0.95f);
            out[((size_t)(b * 510 + h0 + pi)) * 510 + (w0 + pj)] = s;
        }
    }
}

extern "C" void kernel_launch(void* const* d_in, const int* in_sizes, int n_in,
                              void* d_out, int out_size, void* d_ws, size_t ws_size,
                              hipStream_t stream) {
    const float* x       = (const float*)d_in[0];
    const float* sobel_w = (const float*)d_in[1];
    const float* w1      = (const float*)d_in[2];
    const float* b1      = (const float*)d_in[3];
    const float* w2      = (const float*)d_in[4];
    const float* b2      = (const float*)d_in[5];
    float* out = (float*)d_out;
    unsigned short* wtab = (unsigned short*)d_ws;   // 18*64*16 = 18432 B

    prep_w1<<<dim3(18), dim3(64), 0, stream>>>(w1, wtab);
    fasa_mfma<<<dim3(3600), dim3(NT), 0, stream>>>(x, sobel_w, wtab, b1, w2, b2, out);
}